// Round 1
// baseline (154046.741 us; speedup 1.0000x reference)
//
#include <hip/hip_runtime.h>
#include <math.h>

#define BLK 256
#define NWG 256

static constexpr int Bc = 32, Tc = 128, Dc = 512, Vc = 97, Hc = 8, DHc = 64;
static constexpr int Wc = 8, Nc = 128, Mc = 64, FFc = 2048, WIDEc = 576;

// ---- workspace layout (in floats) ----
static constexpr size_t OFF_WFT = 0,               SZ_WFT = 576 * 1536;   // fused (Wqkv@W_in)^T [c][j]
static constexpr size_t OFF_BF  = OFF_WFT + SZ_WFT, SZ_BF  = 1536;        // fused qkv bias
static constexpr size_t OFF_WINT= OFF_BF  + SZ_BF,  SZ_WINT= 576 * 512;   // W_in^T [c][f]
static constexpr size_t OFF_WOT = OFF_WINT+ SZ_WINT,SZ_WOT = 512 * 512;   // W_o^T [e][c]
static constexpr size_t OFF_FF1T= OFF_WOT + SZ_WOT, SZ_FF1T= 512 * 2048;  // W_ff1^T [d][f]
static constexpr size_t OFF_FF2T= OFF_FF1T+ SZ_FF1T,SZ_FF2T= 2048 * 512;  // W_ff2^T [k][c]
static constexpr size_t OFF_KC  = OFF_FF2T+ SZ_FF2T,SZ_KC  = 32*8*8*64;   // k cache [b][h][slot][e]
static constexpr size_t OFF_VC  = OFF_KC  + SZ_KC,  SZ_VC  = 32*8*8*64;
static constexpr size_t OFF_YP  = OFF_VC  + SZ_VC,  SZ_YP  = 8*32*512;    // y partials [h][b][c]
static constexpr size_t OFF_X2  = OFF_YP  + SZ_YP,  SZ_X2  = 32*512;
static constexpr size_t OFF_FP  = OFF_X2  + SZ_X2,  SZ_FP  = 8*32*512;    // ff2 partials [ks][b][c]
static constexpr size_t OFF_RB  = OFF_FP  + SZ_FP,  SZ_RB  = 32*64;       // r (read vector)
static constexpr size_t OFF_RW  = OFF_RB  + SZ_RB,  SZ_RW  = 32*128;      // read weights w
static constexpr size_t OFF_WW  = OFF_RW  + SZ_RW,  SZ_WW  = 32*128;      // write weights w
static constexpr size_t OFF_MEM = OFF_WW  + SZ_WW,  SZ_MEM = 32*128*64;   // NTM memory
static constexpr size_t OFF_BAR = OFF_MEM + SZ_MEM;                       // 2 ints

// ---------------- helpers ----------------
__device__ __forceinline__ float warp_sum(float v) {
#pragma unroll
  for (int o = 32; o; o >>= 1) v += __shfl_down(v, o);
  return v;
}
__device__ __forceinline__ float block_sum(float v, float* red) {
  v = warp_sum(v);
  int wv = threadIdx.x >> 6, ln = threadIdx.x & 63;
  __syncthreads();
  if (ln == 0) red[wv] = v;
  __syncthreads();
  return red[0] + red[1] + red[2] + red[3];
}
__device__ __forceinline__ float block_max(float v, float* red) {
#pragma unroll
  for (int o = 32; o; o >>= 1) v = fmaxf(v, __shfl_down(v, o));
  int wv = threadIdx.x >> 6, ln = threadIdx.x & 63;
  __syncthreads();
  if (ln == 0) red[wv] = v;
  __syncthreads();
  return fmaxf(fmaxf(red[0], red[1]), fmaxf(red[2], red[3]));
}
__device__ __forceinline__ float softplusf_(float x) { return x > 20.f ? x : log1pf(expf(x)); }
__device__ __forceinline__ float sigmoidf_(float x) { return 1.f / (1.f + expf(-x)); }

__device__ __forceinline__ void gbar(int* bar) {
  __threadfence();
  __syncthreads();
  if (threadIdx.x == 0) {
    int* cnt = bar;
    int* gen = bar + 1;
    int g = __hip_atomic_load(gen, __ATOMIC_RELAXED, __HIP_MEMORY_SCOPE_AGENT);
    int v = __hip_atomic_fetch_add(cnt, 1, __ATOMIC_ACQ_REL, __HIP_MEMORY_SCOPE_AGENT);
    if (v == NWG - 1) {
      __hip_atomic_store(cnt, 0, __ATOMIC_RELAXED, __HIP_MEMORY_SCOPE_AGENT);
      __hip_atomic_store(gen, g + 1, __ATOMIC_RELEASE, __HIP_MEMORY_SCOPE_AGENT);
    } else {
      while (__hip_atomic_load(gen, __ATOMIC_ACQUIRE, __HIP_MEMORY_SCOPE_AGENT) == g)
        __builtin_amdgcn_s_sleep(2);
    }
  }
  __syncthreads();
  __threadfence();
}

// NTM addressing: par = [key(64), beta, gate, shift(3), gamma] in LDS
__device__ void addressing(const float* par, const float* prevw, const float* memb,
                           float* wout, float* cosv, float* wgv, float* red) {
  const int tid = threadIdx.x, ln = tid & 63, wv = tid >> 6;
  float knorm2 = block_sum((tid < 64) ? par[tid] * par[tid] : 0.f, red);
  float kinv = 1.f / (sqrtf(knorm2) + 1e-12f);
  for (int n = wv; n < 128; n += 4) {
    float me = memb[n * 64 + ln];
    float p = warp_sum(me * par[ln]);
    float q = warp_sum(me * me);
    if (ln == 0) cosv[n] = p * kinv / (sqrtf(q) + 1e-12f);
  }
  __syncthreads();
  float beta = softplusf_(par[64]);
  float val = (tid < 128) ? beta * cosv[tid] : -INFINITY;
  float mx = block_max(val, red);
  float e = (tid < 128) ? expf(val - mx) : 0.f;
  float ssum = block_sum(e, red);
  float g = sigmoidf_(par[65]);
  if (tid < 128) wgv[tid] = g * (e / ssum) + (1.f - g) * prevw[tid];
  float s0 = par[66], s1 = par[67], s2 = par[68];
  float m3 = fmaxf(s0, fmaxf(s1, s2));
  float e0 = expf(s0 - m3), e1 = expf(s1 - m3), e2 = expf(s2 - m3);
  float inv3 = 1.f / (e0 + e1 + e2);
  e0 *= inv3; e1 *= inv3; e2 *= inv3;
  float gp = 1.f + softplusf_(par[69]);
  __syncthreads();
  float wt = 0.f;
  if (tid < 128) {
    float sh = e0 * wgv[(tid + 1) & 127] + e1 * wgv[tid] + e2 * wgv[(tid - 1) & 127];
    wt = powf(sh + 1e-12f, gp);
  }
  float wsum = block_sum(wt, red);
  if (tid < 128) wout[tid] = wt / (wsum + 1e-12f);
  __syncthreads();
}

// ---------------- init: transposes, fused bias, state ----------------
__global__ __launch_bounds__(256) void k_init(const float* W_in, const float* W_o,
                                              const float* W_ff1, const float* W_ff2,
                                              const float* W_qkv, const float* b_qkv,
                                              const float* b_in, float* ws) {
  const size_t tid = (size_t)blockIdx.x * blockDim.x + threadIdx.x;
  const size_t nth = (size_t)gridDim.x * blockDim.x;
  for (size_t i = tid; i < SZ_WINT; i += nth) { size_t c = i / 512, f = i % 512; ws[OFF_WINT + i] = W_in[f * 576 + c]; }
  for (size_t i = tid; i < SZ_WOT; i += nth)  { size_t e = i / 512, c = i % 512; ws[OFF_WOT + i] = W_o[c * 512 + e]; }
  for (size_t i = tid; i < SZ_FF1T; i += nth) { size_t d = i / 2048, f = i % 2048; ws[OFF_FF1T + i] = W_ff1[f * 512 + d]; }
  for (size_t i = tid; i < SZ_FF2T; i += nth) { size_t k = i / 512, c = i % 512; ws[OFF_FF2T + i] = W_ff2[c * 2048 + k]; }
  for (size_t j = tid; j < 1536; j += nth) {
    float a = b_qkv[j];
    const float* r = W_qkv + j * 512;
    for (int d = 0; d < 512; ++d) a += r[d] * b_in[d];
    ws[OFF_BF + j] = a;
  }
  for (size_t i = tid; i < SZ_MEM; i += nth) ws[OFF_MEM + i] = 0.f;
  for (size_t i = tid; i < SZ_RW; i += nth) {
    float v = ((i & 127) == 0) ? 1.f : 0.f;
    ws[OFF_RW + i] = v;
    ws[OFF_WW + i] = v;
  }
  for (size_t i = tid; i < SZ_RB; i += nth) ws[OFF_RB + i] = 0.f;
  if (tid < 2) ((int*)(ws + OFF_BAR))[tid] = 0;
}

// ---------------- fused weight: WfusedT[c][j] = sum_d W_in[d][c]*W_qkv[j][d] ----------------
__global__ __launch_bounds__(256) void k_fuse(const float* W_qkv, const float* W_in, float* ws) {
  __shared__ float As[32][64];   // W_in[d][c] tile
  __shared__ float Bs[32][96];   // W_qkv[j][d] tile (transposed)
  const int cb = blockIdx.x % 9, jb = blockIdx.x / 9;
  const int c0 = cb * 64, j0 = jb * 96;
  const int tid = threadIdx.x;
  float acc[24];
#pragma unroll
  for (int u = 0; u < 24; ++u) acc[u] = 0.f;
  for (int d0 = 0; d0 < 512; d0 += 32) {
    __syncthreads();
    for (int i = tid; i < 32 * 64; i += 256) { int dd = i >> 6, cc = i & 63; As[dd][cc] = W_in[(size_t)(d0 + dd) * 576 + c0 + cc]; }
    for (int i = tid; i < 32 * 96; i += 256) { int jj = i >> 5, dd = i & 31; Bs[dd][jj] = W_qkv[(size_t)(j0 + jj) * 512 + d0 + dd]; }
    __syncthreads();
    const int tc = tid & 63, jbase = (tid >> 6) * 24;
    for (int dd = 0; dd < 32; ++dd) {
      float a = As[dd][tc];
#pragma unroll
      for (int u = 0; u < 24; ++u) acc[u] += a * Bs[dd][jbase + u];
    }
  }
  const int tc = tid & 63, jbase = (tid >> 6) * 24;
#pragma unroll
  for (int u = 0; u < 24; ++u)
    ws[OFF_WFT + (size_t)(c0 + tc) * 1536 + j0 + jbase + u] = acc[u];
}

// ---------------- persistent main kernel ----------------
__global__ __launch_bounds__(BLK) void k_main(
    const int* x, const float* emb, const float* b_in, const float* b_o,
    const float* ln1g, const float* ln1b, const float* b_ff1, const float* b_ff2,
    const float* ln2g, const float* ln2b, const float* W_tok, const float* b_tok,
    const float* W_read, const float* b_read, const float* W_write, const float* b_write,
    float* ws, float* dout) {
  const int wg = blockIdx.x, tid = threadIdx.x;
  int* bar = (int*)(ws + OFF_BAR);

  __shared__ float s_wide[576];
  __shared__ float s_q[64], s_k[64], s_v[64], s_xp[64];
  __shared__ float s_sc[8], s_aw[8];
  __shared__ float s_ctx[64];
  __shared__ float s_row[512];    // yrow / orow
  __shared__ float s_row2[512];   // x2row / outrow
  __shared__ float s_h[256];
  __shared__ float s_rp[72], s_wp[200];
  __shared__ float s_cos[128], s_wgv[128], s_rwn[128], s_wwn[128];
  __shared__ float s_er[64], s_ad[64];
  __shared__ float s_red[4];

  for (int t = 0; t < Tc; ++t) {
    // ================= P1: qkv (fused) + attention + W_o partial + xp =================
    {
      const int b = wg >> 3, h = wg & 7;
      const int tok = x[b * Tc + t];
      for (int i = tid; i < WIDEc; i += BLK)
        s_wide[i] = (i < 512) ? emb[(size_t)tok * 512 + i] : ws[OFF_RB + b * 64 + (i - 512)];
      __syncthreads();
      {
        const int part = tid >> 6, f = tid & 63;
        const float* col;
        int str;
        float acc;
        if (part < 3) { int j = part * 512 + h * 64 + f; col = ws + OFF_WFT + j; str = 1536; acc = ws[OFF_BF + j]; }
        else          { int j = h * 64 + f;              col = ws + OFF_WINT + j; str = 512;  acc = b_in[j]; }
#pragma unroll 4
        for (int c = 0; c < WIDEc; ++c) acc += s_wide[c] * col[c * str];
        const int slot = t & 7;
        if (part == 0) s_q[f] = acc;
        else if (part == 1) { s_k[f] = acc; ws[OFF_KC + ((size_t)(b * 8 + h) * 8 + slot) * 64 + f] = acc; }
        else if (part == 2) { s_v[f] = acc; ws[OFF_VC + ((size_t)(b * 8 + h) * 8 + slot) * 64 + f] = acc; }
        else s_xp[f] = acc;
      }
      __syncthreads();
      {
        const int ln = tid & 63, wv = tid >> 6;
        for (int rep = 0; rep < 2; ++rep) {
          int j = wv + rep * 4, st = t - 7 + j;
          float p = 0.f;
          if (st >= 0) {
            float kv = (st == t) ? s_k[ln] : ws[OFF_KC + ((size_t)(b * 8 + h) * 8 + (st & 7)) * 64 + ln];
            p = s_q[ln] * kv;
          }
          p = warp_sum(p);
          if (ln == 0) s_sc[j] = (st >= 0) ? p * 0.125f : -INFINITY;
        }
      }
      __syncthreads();
      if (tid == 0) {
        float mx = -INFINITY;
        for (int j = 0; j < 8; ++j) mx = fmaxf(mx, s_sc[j]);
        float ssm = 0.f;
        for (int j = 0; j < 8; ++j) { float e = expf(s_sc[j] - mx); s_aw[j] = e; ssm += e; }
        float inv = 1.f / ssm;
        for (int j = 0; j < 8; ++j) s_aw[j] *= inv;
      }
      __syncthreads();
      if (tid < 64) {
        float a = 0.f;
        for (int j = 0; j < 8; ++j) {
          int st = t - 7 + j;
          if (st < 0) continue;
          float vv = (st == t) ? s_v[tid] : ws[OFF_VC + ((size_t)(b * 8 + h) * 8 + (st & 7)) * 64 + tid];
          a += s_aw[j] * vv;
        }
        s_ctx[tid] = a;
      }
      __syncthreads();
      for (int c = tid; c < 512; c += BLK) {
        float a = (h == 0) ? b_o[c] : 0.f;
#pragma unroll 8
        for (int e = 0; e < 64; ++e) a += s_ctx[e] * ws[OFF_WOT + (size_t)(h * 64 + e) * 512 + c];
        if ((c >> 6) == h) a += s_xp[c & 63];
        ws[OFF_YP + (size_t)(h * 32 + b) * 512 + c] = a;
      }
    }
    gbar(bar);

    // ================= P2: y-sum + LN1 + ff1 + gelu + ff2 partial =================
    {
      const int b = wg >> 3, ks = wg & 7;
      for (int c = tid; c < 512; c += BLK) {
        float a = 0.f;
#pragma unroll
        for (int hh = 0; hh < 8; ++hh) a += ws[OFF_YP + (size_t)(hh * 32 + b) * 512 + c];
        s_row[c] = a;
      }
      __syncthreads();
      float lv = 0.f;
      for (int c = tid; c < 512; c += BLK) lv += s_row[c];
      float mu = block_sum(lv, s_red) * (1.f / 512.f);
      float ld = 0.f;
      for (int c = tid; c < 512; c += BLK) { float d = s_row[c] - mu; ld += d * d; }
      float var = block_sum(ld, s_red) * (1.f / 512.f);
      float rstd = rsqrtf(var + 1e-5f);
      for (int c = tid; c < 512; c += BLK) s_row2[c] = (s_row[c] - mu) * rstd * ln1g[c] + ln1b[c];
      __syncthreads();
      if (ks == 0)
        for (int c = tid; c < 512; c += BLK) ws[OFF_X2 + (size_t)b * 512 + c] = s_row2[c];
      {
        const int f = ks * 256 + tid;
        float a = b_ff1[f];
#pragma unroll 4
        for (int d = 0; d < 512; ++d) a += s_row2[d] * ws[OFF_FF1T + (size_t)d * 2048 + f];
        s_h[tid] = 0.5f * a * (1.f + erff(a * 0.70710678f));
      }
      __syncthreads();
      for (int c = tid; c < 512; c += BLK) {
        float a = 0.f;
#pragma unroll 4
        for (int kk = 0; kk < 256; ++kk) a += s_h[kk] * ws[OFF_FF2T + (size_t)(ks * 256 + kk) * 512 + c];
        ws[OFF_FP + (size_t)(ks * 32 + b) * 512 + c] = a;
      }
    }
    gbar(bar);

    // ================= P3: LN2 + logits / rp,wp + addressing + memory =================
    {
      int b, piece = -1;
      if (wg < 32) b = wg;
      else { b = (wg - 32) / 7; piece = (wg - 32) % 7; }
      for (int c = tid; c < 512; c += BLK) {
        float a = ws[OFF_X2 + (size_t)b * 512 + c] + b_ff2[c];
#pragma unroll
        for (int ks = 0; ks < 8; ++ks) a += ws[OFF_FP + (size_t)(ks * 32 + b) * 512 + c];
        s_row[c] = a;
      }
      __syncthreads();
      float lv = 0.f;
      for (int c = tid; c < 512; c += BLK) lv += s_row[c];
      float mu = block_sum(lv, s_red) * (1.f / 512.f);
      float ld = 0.f;
      for (int c = tid; c < 512; c += BLK) { float d = s_row[c] - mu; ld += d * d; }
      float var = block_sum(ld, s_red) * (1.f / 512.f);
      float rstd = rsqrtf(var + 1e-5f);
      for (int c = tid; c < 512; c += BLK) s_row2[c] = (s_row[c] - mu) * rstd * ln2g[c] + ln2b[c];
      __syncthreads();
      const int ln = tid & 63, wv = tid >> 6;
      if (piece >= 0) {
        // helper: logits slice
        int v0 = piece * 14;
        int v1 = v0 + 14; if (v1 > 97) v1 = 97;
        for (int rep = 0; rep < 4; ++rep) {
          int v = v0 + wv + rep * 4;
          if (v < v1) {
            float p = 0.f;
            for (int d = ln; d < 512; d += 64) p += s_row2[d] * W_tok[(size_t)v * 512 + d];
            p = warp_sum(p);
            if (ln == 0) dout[((size_t)b * Tc + t) * Vc + v] = p + b_tok[v];
          }
        }
      } else {
        // owner: rp/wp + addressing + memory update + r
        for (int jj = wv; jj < 268; jj += 4) {
          const float* row;
          float bias;
          if (jj < 70) { row = W_read + (size_t)jj * 512; bias = b_read[jj]; }
          else { row = W_write + (size_t)(jj - 70) * 512; bias = b_write[jj - 70]; }
          float p = 0.f;
          for (int d = ln; d < 512; d += 64) p += s_row2[d] * row[d];
          p = warp_sum(p);
          if (ln == 0) { if (jj < 70) s_rp[jj] = p + bias; else s_wp[jj - 70] = p + bias; }
        }
        __syncthreads();
        float* memb = ws + OFF_MEM + (size_t)b * 8192;
        addressing(s_rp, ws + OFF_RW + (size_t)b * 128, memb, s_rwn, s_cos, s_wgv, s_red);
        addressing(s_wp, ws + OFF_WW + (size_t)b * 128, memb, s_wwn, s_cos, s_wgv, s_red);
        if (tid < 64) { s_er[tid] = sigmoidf_(s_wp[70 + tid]); s_ad[tid] = tanhf(s_wp[134 + tid]); }
        __syncthreads();
        for (int idx = tid; idx < 8192; idx += BLK) {
          int n = idx >> 6, m = idx & 63;
          float mm = memb[idx];
          memb[idx] = mm * (1.f - s_wwn[n] * s_er[m]) + s_wwn[n] * s_ad[m];
        }
        if (tid < 128) {
          ws[OFF_RW + (size_t)b * 128 + tid] = s_rwn[tid];
          ws[OFF_WW + (size_t)b * 128 + tid] = s_wwn[tid];
        }
        __syncthreads();
        if (tid < 64) {
          float a = 0.f;
          for (int n = 0; n < 128; ++n) a += s_rwn[n] * memb[n * 64 + tid];
          ws[OFF_RB + (size_t)b * 64 + tid] = a;
        }
      }
    }
    gbar(bar);
  }
}

extern "C" void kernel_launch(void* const* d_in, const int* in_sizes, int n_in,
                              void* d_out, int out_size, void* d_ws, size_t ws_size,
                              hipStream_t stream) {
  (void)in_sizes; (void)n_in; (void)out_size; (void)ws_size;
  const int* x = (const int*)d_in[0];
  const float* emb = (const float*)d_in[1];
  const float* W_in = (const float*)d_in[2];
  const float* b_in = (const float*)d_in[3];
  const float* W_qkv = (const float*)d_in[4];
  const float* b_qkv = (const float*)d_in[5];
  const float* W_o = (const float*)d_in[6];
  const float* b_o = (const float*)d_in[7];
  const float* ln1g = (const float*)d_in[8];
  const float* ln1b = (const float*)d_in[9];
  const float* W_ff1 = (const float*)d_in[10];
  const float* b_ff1 = (const float*)d_in[11];
  const float* W_ff2 = (const float*)d_in[12];
  const float* b_ff2 = (const float*)d_in[13];
  const float* ln2g = (const float*)d_in[14];
  const float* ln2b = (const float*)d_in[15];
  const float* W_tok = (const float*)d_in[16];
  const float* b_tok = (const float*)d_in[17];
  const float* W_read = (const float*)d_in[18];
  const float* b_read = (const float*)d_in[19];
  const float* W_write = (const float*)d_in[20];
  const float* b_write = (const float*)d_in[21];
  float* ws = (float*)d_ws;
  float* out = (float*)d_out;

  hipLaunchKernelGGL(k_init, dim3(256), dim3(256), 0, stream,
                     W_in, W_o, W_ff1, W_ff2, W_qkv, b_qkv, b_in, ws);
  hipLaunchKernelGGL(k_fuse, dim3(144), dim3(256), 0, stream, W_qkv, W_in, ws);
  hipLaunchKernelGGL(k_main, dim3(NWG), dim3(BLK), 0, stream,
                     x, emb, b_in, b_o, ln1g, ln1b, b_ff1, b_ff2, ln2g, ln2b,
                     W_tok, b_tok, W_read, b_read, W_write, b_write, ws, out);
}

// Round 2
// 76763.477 us; speedup vs baseline: 2.0068x; 2.0068x over previous
//
#include <hip/hip_runtime.h>
#include <math.h>

#define BLK 256
#define NWG 256

static constexpr int Bc = 32, Tc = 128, Dc = 512, Vc = 97, Hc = 8, DHc = 64;
static constexpr int Wc = 8, Nc = 128, Mc = 64, FFc = 2048, WIDEc = 576;

// ---- workspace layout (in floats) ----
static constexpr size_t OFF_WFT = 0,               SZ_WFT = 576 * 1536;   // fused (Wqkv@W_in)^T [c][j]
static constexpr size_t OFF_BF  = OFF_WFT + SZ_WFT, SZ_BF  = 1536;        // fused qkv bias
static constexpr size_t OFF_WINT= OFF_BF  + SZ_BF,  SZ_WINT= 576 * 512;   // W_in^T [c][f]
static constexpr size_t OFF_WOT = OFF_WINT+ SZ_WINT,SZ_WOT = 512 * 512;   // W_o^T [e][c]
static constexpr size_t OFF_FF1T= OFF_WOT + SZ_WOT, SZ_FF1T= 512 * 2048;  // W_ff1^T [d][f]
static constexpr size_t OFF_FF2T= OFF_FF1T+ SZ_FF1T,SZ_FF2T= 2048 * 512;  // W_ff2^T [k][c]
static constexpr size_t OFF_KC  = OFF_FF2T+ SZ_FF2T,SZ_KC  = 32*8*8*64;   // k cache [b][h][slot][e]
static constexpr size_t OFF_VC  = OFF_KC  + SZ_KC,  SZ_VC  = 32*8*8*64;
static constexpr size_t OFF_YP  = OFF_VC  + SZ_VC,  SZ_YP  = 8*32*512;    // y partials [h][b][c]
static constexpr size_t OFF_X2  = OFF_YP  + SZ_YP,  SZ_X2  = 32*512;
static constexpr size_t OFF_FP  = OFF_X2  + SZ_X2,  SZ_FP  = 8*32*512;    // ff2 partials [ks][b][c]
static constexpr size_t OFF_RB  = OFF_FP  + SZ_FP,  SZ_RB  = 32*64;       // r (read vector)
static constexpr size_t OFF_RW  = OFF_RB  + SZ_RB,  SZ_RW  = 32*128;      // read weights w
static constexpr size_t OFF_WW  = OFF_RW  + SZ_RW,  SZ_WW  = 32*128;      // write weights w
static constexpr size_t OFF_MEM = OFF_WW  + SZ_WW,  SZ_MEM = 32*128*64;   // NTM memory
static constexpr size_t OFF_WRWT= OFF_MEM + SZ_MEM, SZ_WRWT= 512 * 272;   // [d][row] rows: 0..69 read, 70..267 write
static constexpr size_t OFF_BAR = OFF_WRWT+ SZ_WRWT;                      // 4096 ints (padded barrier lines)

// ---------------- helpers ----------------
__device__ __forceinline__ float warp_sum(float v) {
#pragma unroll
  for (int o = 32; o; o >>= 1) v += __shfl_down(v, o);
  return v;
}
__device__ __forceinline__ float block_sum(float v, float* red) {
  v = warp_sum(v);
  int wv = threadIdx.x >> 6, ln = threadIdx.x & 63;
  __syncthreads();
  if (ln == 0) red[wv] = v;
  __syncthreads();
  return red[0] + red[1] + red[2] + red[3];
}
__device__ __forceinline__ float block_max(float v, float* red) {
#pragma unroll
  for (int o = 32; o; o >>= 1) v = fmaxf(v, __shfl_down(v, o));
  int wv = threadIdx.x >> 6, ln = threadIdx.x & 63;
  __syncthreads();
  if (ln == 0) red[wv] = v;
  __syncthreads();
  return fmaxf(fmaxf(red[0], red[1]), fmaxf(red[2], red[3]));
}
__device__ __forceinline__ float softplusf_(float x) { return x > 20.f ? x : log1pf(expf(x)); }
__device__ __forceinline__ float sigmoidf_(float x) { return 1.f / (1.f + expf(-x)); }

// Hierarchical epoch barrier: 16 groups x 16 wgs. Counters never reset.
// bar layout (ints): grp[g] at g*64, glob at 1024, flag[g] at 2048+g*64.
__device__ __forceinline__ void gbar(int* bar, int e, int grpid) {
  __threadfence();
  __syncthreads();
  if (threadIdx.x == 0) {
    int* gcnt = bar + grpid * 64;
    int* glob = bar + 1024;
    int* flag = bar + 2048 + grpid * 64;
    int v = __hip_atomic_fetch_add(gcnt, 1, __ATOMIC_ACQ_REL, __HIP_MEMORY_SCOPE_AGENT);
    if (v == 16 * e - 1) {
      int v2 = __hip_atomic_fetch_add(glob, 1, __ATOMIC_ACQ_REL, __HIP_MEMORY_SCOPE_AGENT);
      if (v2 == 16 * e - 1) {
        for (int i = 0; i < 16; ++i)
          __hip_atomic_store(bar + 2048 + i * 64, e, __ATOMIC_RELEASE, __HIP_MEMORY_SCOPE_AGENT);
      } else {
        while (__hip_atomic_load(flag, __ATOMIC_ACQUIRE, __HIP_MEMORY_SCOPE_AGENT) < e)
          __builtin_amdgcn_s_sleep(8);
      }
    } else {
      while (__hip_atomic_load(flag, __ATOMIC_ACQUIRE, __HIP_MEMORY_SCOPE_AGENT) < e)
        __builtin_amdgcn_s_sleep(8);
    }
  }
  __syncthreads();
  __threadfence();
}

// NTM addressing: par = [key(64), beta, gate, shift(3), gamma] in LDS
__device__ void addressing(const float* par, const float* prevw, const float* memb,
                           float* wout, float* cosv, float* wgv, float* red) {
  const int tid = threadIdx.x, ln = tid & 63, wv = tid >> 6;
  float knorm2 = block_sum((tid < 64) ? par[tid] * par[tid] : 0.f, red);
  float kinv = 1.f / (sqrtf(knorm2) + 1e-12f);
  for (int n = wv; n < 128; n += 4) {
    float me = memb[n * 64 + ln];
    float p = warp_sum(me * par[ln]);
    float q = warp_sum(me * me);
    if (ln == 0) cosv[n] = p * kinv / (sqrtf(q) + 1e-12f);
  }
  __syncthreads();
  float beta = softplusf_(par[64]);
  float val = (tid < 128) ? beta * cosv[tid] : -INFINITY;
  float mx = block_max(val, red);
  float e = (tid < 128) ? expf(val - mx) : 0.f;
  float ssum = block_sum(e, red);
  float g = sigmoidf_(par[65]);
  if (tid < 128) wgv[tid] = g * (e / ssum) + (1.f - g) * prevw[tid];
  float s0 = par[66], s1 = par[67], s2 = par[68];
  float m3 = fmaxf(s0, fmaxf(s1, s2));
  float e0 = expf(s0 - m3), e1 = expf(s1 - m3), e2 = expf(s2 - m3);
  float inv3 = 1.f / (e0 + e1 + e2);
  e0 *= inv3; e1 *= inv3; e2 *= inv3;
  float gp = 1.f + softplusf_(par[69]);
  __syncthreads();
  float wt = 0.f;
  if (tid < 128) {
    float sh = e0 * wgv[(tid + 1) & 127] + e1 * wgv[tid] + e2 * wgv[(tid - 1) & 127];
    wt = powf(sh + 1e-12f, gp);
  }
  float wsum = block_sum(wt, red);
  if (tid < 128) wout[tid] = wt / (wsum + 1e-12f);
  __syncthreads();
}

// ---------------- init: transposes, fused bias, state ----------------
__global__ __launch_bounds__(256) void k_init(const float* W_in, const float* W_o,
                                              const float* W_ff1, const float* W_ff2,
                                              const float* W_qkv, const float* b_qkv,
                                              const float* b_in, const float* W_read,
                                              const float* W_write, float* ws) {
  const size_t tid = (size_t)blockIdx.x * blockDim.x + threadIdx.x;
  const size_t nth = (size_t)gridDim.x * blockDim.x;
  for (size_t i = tid; i < SZ_WINT; i += nth) { size_t c = i / 512, f = i % 512; ws[OFF_WINT + i] = W_in[f * 576 + c]; }
  for (size_t i = tid; i < SZ_WOT; i += nth)  { size_t e = i / 512, c = i % 512; ws[OFF_WOT + i] = W_o[c * 512 + e]; }
  for (size_t i = tid; i < SZ_FF1T; i += nth) { size_t d = i / 2048, f = i % 2048; ws[OFF_FF1T + i] = W_ff1[f * 512 + d]; }
  for (size_t i = tid; i < SZ_FF2T; i += nth) { size_t k = i / 512, c = i % 512; ws[OFF_FF2T + i] = W_ff2[c * 2048 + k]; }
  for (size_t i = tid; i < SZ_WRWT; i += nth) {
    size_t d = i / 272, j = i % 272;
    float v = 0.f;
    if (j < 70) v = W_read[j * 512 + d];
    else if (j < 268) v = W_write[(j - 70) * 512 + d];
    ws[OFF_WRWT + i] = v;
  }
  for (size_t j = tid; j < 1536; j += nth) {
    float a = b_qkv[j];
    const float* r = W_qkv + j * 512;
    for (int d = 0; d < 512; ++d) a += r[d] * b_in[d];
    ws[OFF_BF + j] = a;
  }
  for (size_t i = tid; i < SZ_MEM; i += nth) ws[OFF_MEM + i] = 0.f;
  for (size_t i = tid; i < SZ_RW; i += nth) {
    float v = ((i & 127) == 0) ? 1.f : 0.f;
    ws[OFF_RW + i] = v;
    ws[OFF_WW + i] = v;
  }
  for (size_t i = tid; i < SZ_RB; i += nth) ws[OFF_RB + i] = 0.f;
  for (size_t i = tid; i < 4096; i += nth) ((int*)(ws + OFF_BAR))[i] = 0;
}

// ---------------- fused weight: WfusedT[c][j] = sum_d W_in[d][c]*W_qkv[j][d] ----------------
__global__ __launch_bounds__(256) void k_fuse(const float* W_qkv, const float* W_in, float* ws) {
  __shared__ float As[32][64];   // W_in[d][c] tile
  __shared__ float Bs[32][96];   // W_qkv[j][d] tile (transposed)
  const int cb = blockIdx.x % 9, jb = blockIdx.x / 9;
  const int c0 = cb * 64, j0 = jb * 96;
  const int tid = threadIdx.x;
  float acc[24];
#pragma unroll
  for (int u = 0; u < 24; ++u) acc[u] = 0.f;
  for (int d0 = 0; d0 < 512; d0 += 32) {
    __syncthreads();
    for (int i = tid; i < 32 * 64; i += 256) { int dd = i >> 6, cc = i & 63; As[dd][cc] = W_in[(size_t)(d0 + dd) * 576 + c0 + cc]; }
    for (int i = tid; i < 32 * 96; i += 256) { int jj = i >> 5, dd = i & 31; Bs[dd][jj] = W_qkv[(size_t)(j0 + jj) * 512 + d0 + dd]; }
    __syncthreads();
    const int tc = tid & 63, jbase = (tid >> 6) * 24;
    for (int dd = 0; dd < 32; ++dd) {
      float a = As[dd][tc];
#pragma unroll
      for (int u = 0; u < 24; ++u) acc[u] += a * Bs[dd][jbase + u];
    }
  }
  const int tc = tid & 63, jbase = (tid >> 6) * 24;
#pragma unroll
  for (int u = 0; u < 24; ++u)
    ws[OFF_WFT + (size_t)(c0 + tc) * 1536 + j0 + jbase + u] = acc[u];
}

// ---------------- persistent main kernel ----------------
__global__ __launch_bounds__(BLK) void k_main(
    const int* x, const float* emb, const float* b_in, const float* b_o,
    const float* ln1g, const float* ln1b, const float* b_ff1, const float* b_ff2,
    const float* ln2g, const float* ln2b, const float* W_tok, const float* b_tok,
    const float* b_read, const float* b_write,
    float* ws, float* dout) {
  const int wg = blockIdx.x, tid = threadIdx.x;
  int* bar = (int*)(ws + OFF_BAR);
  // group members share an XCD (XCD = wg % 8 dispatch round-robin)
  const int grpid = (wg & 7) * 2 + ((wg >> 3) >> 4);
  int ep = 0;

  __shared__ float s_wide[576];
  __shared__ float s_q[64], s_k[64], s_v[64], s_xp[64];
  __shared__ float s_sc[8], s_aw[8];
  __shared__ float s_ctx[64];
  __shared__ float s_row[512];    // yrow / orow
  __shared__ float s_row2[512];   // x2row / outrow
  __shared__ float s_h[256];
  __shared__ float s_rp[72], s_wp[200];
  __shared__ float s_cos[128], s_wgv[128], s_rwn[128], s_wwn[128];
  __shared__ float s_er[64], s_ad[64];
  __shared__ float s_red[4];

  for (int t = 0; t < Tc; ++t) {
    // ================= P1: qkv (fused) + attention + W_o partial + xp =================
    {
      const int b = wg >> 3, h = wg & 7;
      const int tok = x[b * Tc + t];
      for (int i = tid; i < WIDEc; i += BLK)
        s_wide[i] = (i < 512) ? emb[(size_t)tok * 512 + i] : ws[OFF_RB + b * 64 + (i - 512)];
      __syncthreads();
      {
        const int part = tid >> 6, f = tid & 63;
        float acc;
        if (part < 3) {
          const int j = part * 512 + h * 64 + f;
          const float* col = ws + OFF_WFT + j;
          acc = ws[OFF_BF + j];
#pragma unroll 8
          for (int c = 0; c < WIDEc; ++c) acc += s_wide[c] * col[(size_t)c * 1536];
        } else {
          const int j = h * 64 + f;
          const float* col = ws + OFF_WINT + j;
          acc = b_in[j];
#pragma unroll 8
          for (int c = 0; c < WIDEc; ++c) acc += s_wide[c] * col[(size_t)c * 512];
        }
        const int slot = t & 7;
        if (part == 0) s_q[f] = acc;
        else if (part == 1) { s_k[f] = acc; ws[OFF_KC + ((size_t)(b * 8 + h) * 8 + slot) * 64 + f] = acc; }
        else if (part == 2) { s_v[f] = acc; ws[OFF_VC + ((size_t)(b * 8 + h) * 8 + slot) * 64 + f] = acc; }
        else s_xp[f] = acc;
      }
      __syncthreads();
      {
        const int ln = tid & 63, wv = tid >> 6;
        for (int rep = 0; rep < 2; ++rep) {
          int j = wv + rep * 4, st = t - 7 + j;
          float p = 0.f;
          if (st >= 0) {
            float kv = (st == t) ? s_k[ln] : ws[OFF_KC + ((size_t)(b * 8 + h) * 8 + (st & 7)) * 64 + ln];
            p = s_q[ln] * kv;
          }
          p = warp_sum(p);
          if (ln == 0) s_sc[j] = (st >= 0) ? p * 0.125f : -INFINITY;
        }
      }
      __syncthreads();
      if (tid == 0) {
        float mx = -INFINITY;
        for (int j = 0; j < 8; ++j) mx = fmaxf(mx, s_sc[j]);
        float ssm = 0.f;
        for (int j = 0; j < 8; ++j) { float e = expf(s_sc[j] - mx); s_aw[j] = e; ssm += e; }
        float inv = 1.f / ssm;
        for (int j = 0; j < 8; ++j) s_aw[j] *= inv;
      }
      __syncthreads();
      if (tid < 64) {
        float a = 0.f;
        for (int j = 0; j < 8; ++j) {
          int st = t - 7 + j;
          if (st < 0) continue;
          float vv = (st == t) ? s_v[tid] : ws[OFF_VC + ((size_t)(b * 8 + h) * 8 + (st & 7)) * 64 + tid];
          a += s_aw[j] * vv;
        }
        s_ctx[tid] = a;
      }
      __syncthreads();
      for (int c = tid; c < 512; c += BLK) {
        float a = (h == 0) ? b_o[c] : 0.f;
#pragma unroll 16
        for (int e = 0; e < 64; ++e) a += s_ctx[e] * ws[OFF_WOT + (size_t)(h * 64 + e) * 512 + c];
        if ((c >> 6) == h) a += s_xp[c & 63];
        ws[OFF_YP + (size_t)(h * 32 + b) * 512 + c] = a;
      }
    }
    gbar(bar, ++ep, grpid);

    // ================= P2: y-sum + LN1 + ff1 + gelu + ff2 partial =================
    {
      const int b = wg >> 3, ks = wg & 7;
      for (int c = tid; c < 512; c += BLK) {
        float a = 0.f;
#pragma unroll
        for (int hh = 0; hh < 8; ++hh) a += ws[OFF_YP + (size_t)(hh * 32 + b) * 512 + c];
        s_row[c] = a;
      }
      __syncthreads();
      float lv = 0.f;
      for (int c = tid; c < 512; c += BLK) lv += s_row[c];
      float mu = block_sum(lv, s_red) * (1.f / 512.f);
      float ld = 0.f;
      for (int c = tid; c < 512; c += BLK) { float d = s_row[c] - mu; ld += d * d; }
      float var = block_sum(ld, s_red) * (1.f / 512.f);
      float rstd = rsqrtf(var + 1e-5f);
      for (int c = tid; c < 512; c += BLK) s_row2[c] = (s_row[c] - mu) * rstd * ln1g[c] + ln1b[c];
      __syncthreads();
      if (ks == 0)
        for (int c = tid; c < 512; c += BLK) ws[OFF_X2 + (size_t)b * 512 + c] = s_row2[c];
      {
        const int f = ks * 256 + tid;
        float a = b_ff1[f];
#pragma unroll 8
        for (int d = 0; d < 512; ++d) a += s_row2[d] * ws[OFF_FF1T + (size_t)d * 2048 + f];
        s_h[tid] = 0.5f * a * (1.f + erff(a * 0.70710678f));
      }
      __syncthreads();
      for (int c = tid; c < 512; c += BLK) {
        float a = 0.f;
#pragma unroll 8
        for (int kk = 0; kk < 256; ++kk) a += s_h[kk] * ws[OFF_FF2T + (size_t)(ks * 256 + kk) * 512 + c];
        ws[OFF_FP + (size_t)(ks * 32 + b) * 512 + c] = a;
      }
    }
    gbar(bar, ++ep, grpid);

    // ================= P3: LN2 + logits / rp,wp + addressing + memory =================
    {
      int b, piece = -1;
      if (wg < 32) b = wg;
      else { b = (wg - 32) / 7; piece = (wg - 32) % 7; }
      for (int c = tid; c < 512; c += BLK) {
        float a = ws[OFF_X2 + (size_t)b * 512 + c] + b_ff2[c];
#pragma unroll
        for (int ks = 0; ks < 8; ++ks) a += ws[OFF_FP + (size_t)(ks * 32 + b) * 512 + c];
        s_row[c] = a;
      }
      __syncthreads();
      float lv = 0.f;
      for (int c = tid; c < 512; c += BLK) lv += s_row[c];
      float mu = block_sum(lv, s_red) * (1.f / 512.f);
      float ld = 0.f;
      for (int c = tid; c < 512; c += BLK) { float d = s_row[c] - mu; ld += d * d; }
      float var = block_sum(ld, s_red) * (1.f / 512.f);
      float rstd = rsqrtf(var + 1e-5f);
      for (int c = tid; c < 512; c += BLK) s_row2[c] = (s_row[c] - mu) * rstd * ln2g[c] + ln2b[c];
      __syncthreads();
      const int ln = tid & 63, wv = tid >> 6;
      if (piece >= 0) {
        // helper: logits slice
        int v0 = piece * 14;
        int v1 = v0 + 14; if (v1 > 97) v1 = 97;
        for (int rep = 0; rep < 4; ++rep) {
          int v = v0 + wv + rep * 4;
          if (v < v1) {
            float p = 0.f;
            for (int d = ln; d < 512; d += 64) p += s_row2[d] * W_tok[(size_t)v * 512 + d];
            p = warp_sum(p);
            if (ln == 0) dout[((size_t)b * Tc + t) * Vc + v] = p + b_tok[v];
          }
        }
      } else {
        // owner: rp/wp via transposed streamed matvec + addressing + memory update + r
        for (int r = tid; r < 268; r += BLK) {
          float a = (r < 70) ? b_read[r] : b_write[r - 70];
#pragma unroll 8
          for (int d = 0; d < 512; ++d) a += s_row2[d] * ws[OFF_WRWT + (size_t)d * 272 + r];
          if (r < 70) s_rp[r] = a; else s_wp[r - 70] = a;
        }
        __syncthreads();
        float* memb = ws + OFF_MEM + (size_t)b * 8192;
        addressing(s_rp, ws + OFF_RW + (size_t)b * 128, memb, s_rwn, s_cos, s_wgv, s_red);
        addressing(s_wp, ws + OFF_WW + (size_t)b * 128, memb, s_wwn, s_cos, s_wgv, s_red);
        if (tid < 64) { s_er[tid] = sigmoidf_(s_wp[70 + tid]); s_ad[tid] = tanhf(s_wp[134 + tid]); }
        __syncthreads();
        for (int idx = tid; idx < 8192; idx += BLK) {
          int n = idx >> 6, m = idx & 63;
          float mm = memb[idx];
          memb[idx] = mm * (1.f - s_wwn[n] * s_er[m]) + s_wwn[n] * s_ad[m];
        }
        if (tid < 128) {
          ws[OFF_RW + (size_t)b * 128 + tid] = s_rwn[tid];
          ws[OFF_WW + (size_t)b * 128 + tid] = s_wwn[tid];
        }
        __syncthreads();
        if (tid < 64) {
          float a = 0.f;
#pragma unroll 8
          for (int n = 0; n < 128; ++n) a += s_rwn[n] * memb[n * 64 + tid];
          ws[OFF_RB + (size_t)b * 64 + tid] = a;
        }
      }
    }
    gbar(bar, ++ep, grpid);
  }
}

extern "C" void kernel_launch(void* const* d_in, const int* in_sizes, int n_in,
                              void* d_out, int out_size, void* d_ws, size_t ws_size,
                              hipStream_t stream) {
  (void)in_sizes; (void)n_in; (void)out_size; (void)ws_size;
  const int* x = (const int*)d_in[0];
  const float* emb = (const float*)d_in[1];
  const float* W_in = (const float*)d_in[2];
  const float* b_in = (const float*)d_in[3];
  const float* W_qkv = (const float*)d_in[4];
  const float* b_qkv = (const float*)d_in[5];
  const float* W_o = (const float*)d_in[6];
  const float* b_o = (const float*)d_in[7];
  const float* ln1g = (const float*)d_in[8];
  const float* ln1b = (const float*)d_in[9];
  const float* W_ff1 = (const float*)d_in[10];
  const float* b_ff1 = (const float*)d_in[11];
  const float* W_ff2 = (const float*)d_in[12];
  const float* b_ff2 = (const float*)d_in[13];
  const float* ln2g = (const float*)d_in[14];
  const float* ln2b = (const float*)d_in[15];
  const float* W_tok = (const float*)d_in[16];
  const float* b_tok = (const float*)d_in[17];
  const float* W_read = (const float*)d_in[18];
  const float* b_read = (const float*)d_in[19];
  const float* W_write = (const float*)d_in[20];
  const float* b_write = (const float*)d_in[21];
  float* ws = (float*)d_ws;
  float* out = (float*)d_out;

  hipLaunchKernelGGL(k_init, dim3(256), dim3(256), 0, stream,
                     W_in, W_o, W_ff1, W_ff2, W_qkv, b_qkv, b_in, W_read, W_write, ws);
  hipLaunchKernelGGL(k_fuse, dim3(144), dim3(256), 0, stream, W_qkv, W_in, ws);
  hipLaunchKernelGGL(k_main, dim3(NWG), dim3(BLK), 0, stream,
                     x, emb, b_in, b_o, ln1g, ln1b, b_ff1, b_ff2, ln2g, ln2b,
                     W_tok, b_tok, b_read, b_write, ws, out);
}